// Round 3
// baseline (807.806 us; speedup 1.0000x reference)
//
#include <hip/hip_runtime.h>
#include <hip/hip_bf16.h>
#include <math.h>

typedef __bf16 v8bf  __attribute__((ext_vector_type(8)));
typedef __bf16 v4bf  __attribute__((ext_vector_type(4)));
typedef float  v16f  __attribute__((ext_vector_type(16)));
typedef float  v4f   __attribute__((ext_vector_type(4)));
typedef float  f4v   __attribute__((ext_vector_type(4)));

// ws layout (floats unless noted):
//   [0..16)      scalars: 0=ce, 1=wsum, 2=w4, 3=ab1, 4=ab2, 5=bm, 8=cor(int)
//   [16..272)    col[256]
//   [512..262656)        weight = w^2  (262144)
//   [262656..17039872)   slots: 256 x 65536 fp32 per-block gram tiles (64 MB)
//   byte 68159488: b1T bf16 [256][256]
//   byte 68290560: b2T bf16 [16][256]
#define OFF_COL   16
#define OFF_WT    512
#define OFF_SLOT  262656
#define B1T_BYTE  68159488
#define B2T_BYTE  68290560
#define ZERO_BYTES 1088     // scalars + col only (slots are fully overwritten)

// ---------------- prep: weight=w^2, sums, b1->bf16 transposed, b2->bf16 padded ----------------
extern "C" __global__ __launch_bounds__(256) void prep_k(
    const float* __restrict__ w, const float* __restrict__ b1,
    const float* __restrict__ b2, float* __restrict__ wsf) {
  float* weight = wsf + OFF_WT;
  __bf16* b1T = (__bf16*)((char*)wsf + B1T_BYTE);
  __bf16* b2T = (__bf16*)((char*)wsf + B2T_BYTE);
  int gid = blockIdx.x * 256 + threadIdx.x;
  float wi = w[gid];
  float wt = wi * wi;
  weight[gid] = wt;
  float s1 = wt, s2 = wt * wt, a1 = 0.f, a2 = 0.f;
  if (gid < 65536) {                 // b1T[h][p] = b1[p][h]
    int h = gid >> 8, p = gid & 255;
    float v = b1[p * 256 + h];
    b1T[gid] = (__bf16)v;
    a1 = fabsf(v);
  }
  if (gid < 4096) {                  // b2T[c][h] = b2[h][c], c padded 10->16 with 0
    int c = gid >> 8, h = gid & 255;
    float v = (c < 10) ? b2[h * 10 + c] : 0.f;
    b2T[gid] = (__bf16)v;
    a2 = fabsf(v);
  }
  #pragma unroll
  for (int off = 32; off > 0; off >>= 1) {
    s1 += __shfl_down(s1, off);
    s2 += __shfl_down(s2, off);
    a1 += __shfl_down(a1, off);
    a2 += __shfl_down(a2, off);
  }
  if ((threadIdx.x & 63) == 0) {
    atomicAdd(&wsf[1], s1);
    atomicAdd(&wsf[2], s2);
    if (blockIdx.x < 256) atomicAdd(&wsf[3], a1);
    if (blockIdx.x < 16)  atomicAdd(&wsf[4], a2);
  }
}

// ---------------- gram = x^T diag(w^2) x  (+ col = x^T w^2) ----------------
// 256 blocks x 1024 K-rows. Double-buffered LDS + register prefetch of the
// next 64-row chunk issued BEFORE the MFMA phase. One barrier per chunk.
// Epilogue: streaming stores to a private per-block slot (no atomics).
extern "C" __global__ __launch_bounds__(512, 2) void gram_k(
    const float* __restrict__ x, float* __restrict__ wsf) {
  const float* weight = wsf + OFF_WT;
  float* slot = wsf + OFF_SLOT + blockIdx.x * 65536;
  __shared__ __bf16 xT[2][256 * 72];   // [buf][col][k64], stride 72
  __shared__ __bf16 wxT[2][256 * 72];
  __shared__ float  wS[1024];          // this block's weights
  const int tid = threadIdx.x;
  const int wv = tid >> 6, L = tid & 63;
  const int l32 = L & 31, lh = L >> 5;
  const int mb = 64 * (wv >> 1), nb = 128 * (wv & 1);
  const int col = tid & 255, rh = tid >> 8;   // lane=column; rh picks 32-row half
  const int base = blockIdx.x * 1024;
  v16f acc[2][4] = {};
  float colAcc = 0.f;
  float xv[32];

  // stage all 1024 weights for this block into LDS
  wS[tid] = weight[base + tid];
  wS[tid + 512] = weight[base + 512 + tid];

  // prologue: load chunk 0 into regs
  #pragma unroll
  for (int j = 0; j < 32; j++)
    xv[j] = x[(base + 32 * rh + j) * 256 + col];
  __syncthreads();                     // wS visible
  #pragma unroll
  for (int s = 0; s < 8; s++) {
    v4bf xa, wa;
    #pragma unroll
    for (int i = 0; i < 4; i++) {
      int kr = 32 * rh + 4 * s + i;
      float v = xv[4 * s + i];
      float wvv = wS[kr] * v;
      colAcc += wvv;
      xa[i] = (__bf16)v;
      wa[i] = (__bf16)wvv;
    }
    *(v4bf*)&xT[0][col * 72 + 32 * rh + 4 * s]  = xa;
    *(v4bf*)&wxT[0][col * 72 + 32 * rh + 4 * s] = wa;
  }
  __syncthreads();                     // buf 0 ready

  for (int ch = 0; ch < 16; ch++) {
    const int cur = ch & 1, nxt = cur ^ 1;
    if (ch < 15) {
      int k0 = base + 64 * (ch + 1);
      #pragma unroll
      for (int j = 0; j < 32; j++)
        xv[j] = x[(k0 + 32 * rh + j) * 256 + col];
    }
    #pragma unroll
    for (int ks = 0; ks < 64; ks += 16) {
      v8bf a0 = *(const v8bf*)&xT[cur][(mb + l32) * 72 + ks + 8 * lh];
      v8bf a1 = *(const v8bf*)&xT[cur][(mb + 32 + l32) * 72 + ks + 8 * lh];
      v8bf b[4];
      #pragma unroll
      for (int tn = 0; tn < 4; tn++)
        b[tn] = *(const v8bf*)&wxT[cur][(nb + 32 * tn + l32) * 72 + ks + 8 * lh];
      #pragma unroll
      for (int tn = 0; tn < 4; tn++) {
        acc[0][tn] = __builtin_amdgcn_mfma_f32_32x32x16_bf16(a0, b[tn], acc[0][tn], 0, 0, 0);
        acc[1][tn] = __builtin_amdgcn_mfma_f32_32x32x16_bf16(a1, b[tn], acc[1][tn], 0, 0, 0);
      }
    }
    if (ch < 15) {
      const int wb = 64 * (ch + 1);
      #pragma unroll
      for (int s = 0; s < 8; s++) {
        v4bf xa, wa;
        #pragma unroll
        for (int i = 0; i < 4; i++) {
          int kr = 32 * rh + 4 * s + i;
          float v = xv[4 * s + i];
          float wvv = wS[wb + kr] * v;
          colAcc += wvv;
          xa[i] = (__bf16)v;
          wa[i] = (__bf16)wvv;
        }
        *(v4bf*)&xT[nxt][col * 72 + 32 * rh + 4 * s]  = xa;
        *(v4bf*)&wxT[nxt][col * 72 + 32 * rh + 4 * s] = wa;
      }
      __syncthreads();
    }
  }

  // epilogue: plain streaming stores to the private slot (no atomics)
  #pragma unroll
  for (int tm = 0; tm < 2; tm++)
    #pragma unroll
    for (int tn = 0; tn < 4; tn++)
      #pragma unroll
      for (int r = 0; r < 16; r++) {
        int row = mb + 32 * tm + (r & 3) + 8 * (r >> 2) + 4 * lh;
        int cg = nb + 32 * tn + l32;
        slot[row * 256 + cg] = acc[tm][tn][r];
      }
  atomicAdd(&wsf[OFF_COL + col], colAcc);
}

// ---------------- gfin: reduce 256 slots + bm regularizer ----------------
extern "C" __global__ __launch_bounds__(256) void gfin_k(float* __restrict__ wsf) {
  __shared__ float partial[4][256];
  const int tid = threadIdx.x;
  const int sg = tid >> 6, l = tid & 63;
  const int row = blockIdx.x;
  const float* slot0 = wsf + OFF_SLOT;
  f4v s = {0.f, 0.f, 0.f, 0.f};
  #pragma unroll 4
  for (int sl = sg; sl < 256; sl += 4)
    s += ((const f4v*)(slot0 + sl * 65536 + row * 256))[l];
  *(f4v*)&partial[sg][4 * l] = s;
  __syncthreads();
  float cr = wsf[OFF_COL + row];
  float ct = wsf[OFF_COL + tid];
  float gv = partial[0][tid] + partial[1][tid] + partial[2][tid] + partial[3][tid];
  float d = gv - cr * ct;
  float bm = (tid != row) ? d * d : 0.f;
  #pragma unroll
  for (int off = 32; off > 0; off >>= 1) bm += __shfl_down(bm, off);
  if (l == 0) atomicAdd(&wsf[5], bm);
}

// ---------------- mlp: hdn=relu(x@b1), dropout, logits, CE, argmax ----------------
// 4096 blocks x 64 rows, 256 threads (round-1 geometry, 160us baseline) +
// gram-style register-prefetch pipeline: chunk k+1 global loads issue before
// chunk k's MFMA phase; du (tm=0) prefetched 2 chunks before consumption.
extern "C" __global__ __launch_bounds__(256, 4) void mlp_k(
    const float* __restrict__ x, const int* __restrict__ y,
    const float* __restrict__ du, float* __restrict__ wsf) {
  const __bf16* b1T = (const __bf16*)((const char*)wsf + B1T_BYTE);
  const __bf16* b2T = (const __bf16*)((const char*)wsf + B2T_BYTE);
  __shared__ union U {
    struct { __bf16 xs[64 * 40]; __bf16 b1s[256 * 40]; } m;   // 5120 + 20480 B
    struct { __bf16 hk[64 * 264]; float lg[64 * 17]; } l;     // 33792 + 4352 B
  } sm;
  const int tid = threadIdx.x;
  const int wv = tid >> 6, L = tid & 63;
  const int l32 = L & 31, lh = L >> 5;
  const int nb = 64 * wv;                    // wave owns 64 h-cols
  const int rowBase = blockIdx.x * 64;

  // staging index map (fixed per thread)
  const int xr = tid >> 3, xc = tid & 7;     // x: rows xr / xr+32, float4 group xc
  const int bnr = tid >> 2, bc = tid & 3;    // b1T: rows 64*i + bnr, v8bf group bc

  v16f acc[2][2] = {};
  f4v  xp0, xp1;
  v8bf bp0, bp1, bp2, bp3;
  float dup[32];                             // du prefetch, tm=0 half

  // prologue: load chunk 0 into regs
  {
    const int kc = 0;
    xp0 = ((const f4v*)x)[(rowBase + xr) * 64 + (kc >> 2) + xc];
    xp1 = ((const f4v*)x)[(rowBase + 32 + xr) * 64 + (kc >> 2) + xc];
    bp0 = *(const v8bf*)&b1T[(bnr      ) * 256 + kc + 8 * bc];
    bp1 = *(const v8bf*)&b1T[(bnr +  64) * 256 + kc + 8 * bc];
    bp2 = *(const v8bf*)&b1T[(bnr + 128) * 256 + kc + 8 * bc];
    bp3 = *(const v8bf*)&b1T[(bnr + 192) * 256 + kc + 8 * bc];
  }

  #pragma unroll
  for (int ch = 0; ch < 8; ch++) {
    __syncthreads();                         // LDS free (prev MFMA done)
    // write staged regs -> LDS
    {
      v4bf o;
      o[0] = (__bf16)xp0[0]; o[1] = (__bf16)xp0[1]; o[2] = (__bf16)xp0[2]; o[3] = (__bf16)xp0[3];
      *(v4bf*)&sm.m.xs[xr * 40 + 4 * xc] = o;
      o[0] = (__bf16)xp1[0]; o[1] = (__bf16)xp1[1]; o[2] = (__bf16)xp1[2]; o[3] = (__bf16)xp1[3];
      *(v4bf*)&sm.m.xs[(xr + 32) * 40 + 4 * xc] = o;
      *(v8bf*)&sm.m.b1s[(bnr      ) * 40 + 8 * bc] = bp0;
      *(v8bf*)&sm.m.b1s[(bnr +  64) * 40 + 8 * bc] = bp1;
      *(v8bf*)&sm.m.b1s[(bnr + 128) * 40 + 8 * bc] = bp2;
      *(v8bf*)&sm.m.b1s[(bnr + 192) * 40 + 8 * bc] = bp3;
    }
    __syncthreads();                         // LDS ready
    // issue next-chunk global loads (land during MFMA + next barrier)
    if (ch < 7) {
      const int kc = 32 * (ch + 1);
      xp0 = ((const f4v*)x)[(rowBase + xr) * 64 + (kc >> 2) + xc];
      xp1 = ((const f4v*)x)[(rowBase + 32 + xr) * 64 + (kc >> 2) + xc];
      bp0 = *(const v8bf*)&b1T[(bnr      ) * 256 + kc + 8 * bc];
      bp1 = *(const v8bf*)&b1T[(bnr +  64) * 256 + kc + 8 * bc];
      bp2 = *(const v8bf*)&b1T[(bnr + 128) * 256 + kc + 8 * bc];
      bp3 = *(const v8bf*)&b1T[(bnr + 192) * 256 + kc + 8 * bc];
    }
    if (ch == 6) {                           // du prefetch, tm=0: ~2 chunks of cover
      #pragma unroll
      for (int tn = 0; tn < 2; tn++)
        #pragma unroll
        for (int r = 0; r < 16; r++) {
          int row = (r & 3) + 8 * (r >> 2) + 4 * lh;
          dup[tn * 16 + r] = du[(rowBase + row) * 256 + nb + 32 * tn + l32];
        }
    }
    // MFMA on staged chunk
    #pragma unroll
    for (int ks = 0; ks < 32; ks += 16) {
      v8bf a0  = *(const v8bf*)&sm.m.xs[(l32) * 40 + ks + 8 * lh];
      v8bf a1  = *(const v8bf*)&sm.m.xs[(32 + l32) * 40 + ks + 8 * lh];
      v8bf b0  = *(const v8bf*)&sm.m.b1s[(nb + l32) * 40 + ks + 8 * lh];
      v8bf b1f = *(const v8bf*)&sm.m.b1s[(nb + 32 + l32) * 40 + ks + 8 * lh];
      acc[0][0] = __builtin_amdgcn_mfma_f32_32x32x16_bf16(a0, b0,  acc[0][0], 0, 0, 0);
      acc[0][1] = __builtin_amdgcn_mfma_f32_32x32x16_bf16(a0, b1f, acc[0][1], 0, 0, 0);
      acc[1][0] = __builtin_amdgcn_mfma_f32_32x32x16_bf16(a1, b0,  acc[1][0], 0, 0, 0);
      acc[1][1] = __builtin_amdgcn_mfma_f32_32x32x16_bf16(a1, b1f, acc[1][1], 0, 0, 0);
    }
  }
  // relu + inverted dropout (C layout: col=lane&31, row=(r&3)+8*(r>>2)+4*lh)
  #pragma unroll
  for (int tn = 0; tn < 2; tn++)
    #pragma unroll
    for (int r = 0; r < 16; r++) {
      float u = dup[tn * 16 + r];            // tm=0: prefetched
      float v = fmaxf(acc[0][tn][r], 0.f);
      acc[0][tn][r] = (u > 0.3f) ? v * (1.0f / 0.7f) : 0.f;
    }
  #pragma unroll
  for (int tn = 0; tn < 2; tn++)
    #pragma unroll
    for (int r = 0; r < 16; r++) {
      int row = 32 + (r & 3) + 8 * (r >> 2) + 4 * lh;
      float u = du[(rowBase + row) * 256 + nb + 32 * tn + l32];  // tm=1: inline
      float v = fmaxf(acc[1][tn][r], 0.f);
      acc[1][tn][r] = (u > 0.3f) ? v * (1.0f / 0.7f) : 0.f;
    }

  // spill P to LDS full-width [64][264]
  __syncthreads();
  #pragma unroll
  for (int tm = 0; tm < 2; tm++)
    #pragma unroll
    for (int tn = 0; tn < 2; tn++)
      #pragma unroll
      for (int r = 0; r < 16; r++) {
        int row = 32 * tm + (r & 3) + 8 * (r >> 2) + 4 * lh;
        int cg = nb + 32 * tn + l32;
        sm.l.hk[row * 264 + cg] = (__bf16)acc[tm][tn][r];
      }
  __syncthreads();
  // logits: wave wv -> m-tile rows [16wv,16wv+16), K=256 via 8x 16x16x32
  v4f lacc = {};
  #pragma unroll
  for (int kk = 0; kk < 8; kk++) {
    v8bf a  = *(const v8bf*)&sm.l.hk[(16 * wv + (L & 15)) * 264 + 32 * kk + 8 * (L >> 4)];
    v8bf bb = *(const v8bf*)&b2T[(L & 15) * 256 + 32 * kk + 8 * (L >> 4)];
    lacc = __builtin_amdgcn_mfma_f32_16x16x32_bf16(a, bb, lacc, 0, 0, 0);
  }
  #pragma unroll
  for (int r = 0; r < 4; r++)
    sm.l.lg[(16 * wv + 4 * (L >> 4) + r) * 17 + (L & 15)] = lacc[r];
  __syncthreads();
  float ce = 0.f;
  int cor = 0;
  if (tid < 64) {
    const float* lr = &sm.l.lg[tid * 17];
    float mx = lr[0];
    int am = 0;
    #pragma unroll
    for (int c = 1; c < 10; c++)
      if (lr[c] > mx) { mx = lr[c]; am = c; }   // strict > = first-max (jnp semantics)
    float s = 0.f;
    #pragma unroll
    for (int c = 0; c < 10; c++) s += expf(lr[c] - mx);
    int yt = y[rowBase + tid];
    ce = logf(s) + mx - lr[yt];
    cor = (am == yt) ? 1 : 0;
  }
  if (wv == 0) {
    #pragma unroll
    for (int off = 32; off > 0; off >>= 1) ce += __shfl_down(ce, off);
    unsigned long long bal = __ballot(cor != 0);
    if (L == 0) {
      atomicAdd(&wsf[0], ce);
      atomicAdd((int*)&wsf[8], (int)__popcll(bal));
    }
  }
}

// ---------------- fin2: scalar combine ----------------
extern "C" __global__ void fin2_k(const float* __restrict__ wsf, float* __restrict__ out) {
  if (threadIdx.x == 0) {
    float ce = wsf[0], wsum = wsf[1], w4 = wsf[2], ab1 = wsf[3], ab2 = wsf[4], bm = wsf[5];
    int cor = ((const int*)wsf)[8];
    float loss = ce * wsum
               + 0.01f * (ab1 + ab2)
               + 0.001f * bm
               + 0.1f * w4
               + 100.f * (wsum - 1.f) * (wsum - 1.f);
    out[0] = loss;
    out[1] = (float)cor * (1.0f / 262144.0f);
  }
}

extern "C" void kernel_launch(void* const* d_in, const int* in_sizes, int n_in,
                              void* d_out, int out_size, void* d_ws, size_t ws_size,
                              hipStream_t stream) {
  const float* x  = (const float*)d_in[0];
  const int*   y  = (const int*)d_in[1];
  const float* du = (const float*)d_in[2];
  const float* b1 = (const float*)d_in[3];
  const float* b2 = (const float*)d_in[4];
  const float* w  = (const float*)d_in[5];
  float* wsf = (float*)d_ws;

  hipMemsetAsync(d_ws, 0, ZERO_BYTES, stream);   // scalars + col only
  prep_k<<<1024, 256, 0, stream>>>(w, b1, b2, wsf);
  gram_k<<<256, 512, 0, stream>>>(x, wsf);       // x stays warm in L3 for mlp
  gfin_k<<<256, 256, 0, stream>>>(wsf);          // slots are L3-hot right here
  mlp_k<<<4096, 256, 0, stream>>>(x, y, du, wsf);
  fin2_k<<<1, 64, 0, stream>>>(wsf, (float*)d_out);
}

// Round 4
// 765.346 us; speedup vs baseline: 1.0555x; 1.0555x over previous
//
#include <hip/hip_runtime.h>
#include <hip/hip_bf16.h>
#include <math.h>

typedef __bf16 v8bf  __attribute__((ext_vector_type(8)));
typedef __bf16 v4bf  __attribute__((ext_vector_type(4)));
typedef float  v16f  __attribute__((ext_vector_type(16)));
typedef float  v4f   __attribute__((ext_vector_type(4)));
typedef float  f4v   __attribute__((ext_vector_type(4)));

// ws layout (floats unless noted):
//   [0..16)      scalars: 0=ce, 1=wsum, 2=w4, 3=ab1, 4=ab2, 5=bm, 8=cor(int)
//   [16..272)    col[256]
//   [512..262656)        weight = w^2  (262144)
//   [262656..17039872)   slots: 256 x 65536 fp32 per-block gram tiles (64 MB)
//   byte 68159488: b1T bf16 [256][256]
//   byte 68290560: b2T bf16 [16][256]
#define OFF_COL   16
#define OFF_WT    512
#define OFF_SLOT  262656
#define B1T_BYTE  68159488
#define B2T_BYTE  68290560
#define ZERO_BYTES 1088     // scalars + col only (slots are fully overwritten)

// ---------------- prep: weight=w^2, sums, b1->bf16 transposed, b2->bf16 padded ----------------
extern "C" __global__ __launch_bounds__(256) void prep_k(
    const float* __restrict__ w, const float* __restrict__ b1,
    const float* __restrict__ b2, float* __restrict__ wsf) {
  float* weight = wsf + OFF_WT;
  __bf16* b1T = (__bf16*)((char*)wsf + B1T_BYTE);
  __bf16* b2T = (__bf16*)((char*)wsf + B2T_BYTE);
  int gid = blockIdx.x * 256 + threadIdx.x;
  float wi = w[gid];
  float wt = wi * wi;
  weight[gid] = wt;
  float s1 = wt, s2 = wt * wt, a1 = 0.f, a2 = 0.f;
  if (gid < 65536) {                 // b1T[h][p] = b1[p][h]
    int h = gid >> 8, p = gid & 255;
    float v = b1[p * 256 + h];
    b1T[gid] = (__bf16)v;
    a1 = fabsf(v);
  }
  if (gid < 4096) {                  // b2T[c][h] = b2[h][c], c padded 10->16 with 0
    int c = gid >> 8, h = gid & 255;
    float v = (c < 10) ? b2[h * 10 + c] : 0.f;
    b2T[gid] = (__bf16)v;
    a2 = fabsf(v);
  }
  #pragma unroll
  for (int off = 32; off > 0; off >>= 1) {
    s1 += __shfl_down(s1, off);
    s2 += __shfl_down(s2, off);
    a1 += __shfl_down(a1, off);
    a2 += __shfl_down(a2, off);
  }
  if ((threadIdx.x & 63) == 0) {
    atomicAdd(&wsf[1], s1);
    atomicAdd(&wsf[2], s2);
    if (blockIdx.x < 256) atomicAdd(&wsf[3], a1);
    if (blockIdx.x < 16)  atomicAdd(&wsf[4], a2);
  }
}

// ---------------- gram = x^T diag(w^2) x  (+ col = x^T w^2) ----------------
// 256 blocks x 1024 K-rows. Double-buffered LDS + register prefetch of the
// next 64-row chunk issued BEFORE the MFMA phase. One barrier per chunk.
// Epilogue: streaming stores to a private per-block slot (no atomics).
extern "C" __global__ __launch_bounds__(512, 2) void gram_k(
    const float* __restrict__ x, float* __restrict__ wsf) {
  const float* weight = wsf + OFF_WT;
  float* slot = wsf + OFF_SLOT + blockIdx.x * 65536;
  __shared__ __bf16 xT[2][256 * 72];   // [buf][col][k64], stride 72
  __shared__ __bf16 wxT[2][256 * 72];
  __shared__ float  wS[1024];          // this block's weights
  const int tid = threadIdx.x;
  const int wv = tid >> 6, L = tid & 63;
  const int l32 = L & 31, lh = L >> 5;
  const int mb = 64 * (wv >> 1), nb = 128 * (wv & 1);
  const int col = tid & 255, rh = tid >> 8;   // lane=column; rh picks 32-row half
  const int base = blockIdx.x * 1024;
  v16f acc[2][4] = {};
  float colAcc = 0.f;
  float xv[32];

  // stage all 1024 weights for this block into LDS
  wS[tid] = weight[base + tid];
  wS[tid + 512] = weight[base + 512 + tid];

  // prologue: load chunk 0 into regs
  #pragma unroll
  for (int j = 0; j < 32; j++)
    xv[j] = x[(base + 32 * rh + j) * 256 + col];
  __syncthreads();                     // wS visible
  #pragma unroll
  for (int s = 0; s < 8; s++) {
    v4bf xa, wa;
    #pragma unroll
    for (int i = 0; i < 4; i++) {
      int kr = 32 * rh + 4 * s + i;
      float v = xv[4 * s + i];
      float wvv = wS[kr] * v;
      colAcc += wvv;
      xa[i] = (__bf16)v;
      wa[i] = (__bf16)wvv;
    }
    *(v4bf*)&xT[0][col * 72 + 32 * rh + 4 * s]  = xa;
    *(v4bf*)&wxT[0][col * 72 + 32 * rh + 4 * s] = wa;
  }
  __syncthreads();                     // buf 0 ready

  for (int ch = 0; ch < 16; ch++) {
    const int cur = ch & 1, nxt = cur ^ 1;
    if (ch < 15) {
      int k0 = base + 64 * (ch + 1);
      #pragma unroll
      for (int j = 0; j < 32; j++)
        xv[j] = x[(k0 + 32 * rh + j) * 256 + col];
    }
    #pragma unroll
    for (int ks = 0; ks < 64; ks += 16) {
      v8bf a0 = *(const v8bf*)&xT[cur][(mb + l32) * 72 + ks + 8 * lh];
      v8bf a1 = *(const v8bf*)&xT[cur][(mb + 32 + l32) * 72 + ks + 8 * lh];
      v8bf b[4];
      #pragma unroll
      for (int tn = 0; tn < 4; tn++)
        b[tn] = *(const v8bf*)&wxT[cur][(nb + 32 * tn + l32) * 72 + ks + 8 * lh];
      #pragma unroll
      for (int tn = 0; tn < 4; tn++) {
        acc[0][tn] = __builtin_amdgcn_mfma_f32_32x32x16_bf16(a0, b[tn], acc[0][tn], 0, 0, 0);
        acc[1][tn] = __builtin_amdgcn_mfma_f32_32x32x16_bf16(a1, b[tn], acc[1][tn], 0, 0, 0);
      }
    }
    if (ch < 15) {
      const int wb = 64 * (ch + 1);
      #pragma unroll
      for (int s = 0; s < 8; s++) {
        v4bf xa, wa;
        #pragma unroll
        for (int i = 0; i < 4; i++) {
          int kr = 32 * rh + 4 * s + i;
          float v = xv[4 * s + i];
          float wvv = wS[wb + kr] * v;
          colAcc += wvv;
          xa[i] = (__bf16)v;
          wa[i] = (__bf16)wvv;
        }
        *(v4bf*)&xT[nxt][col * 72 + 32 * rh + 4 * s]  = xa;
        *(v4bf*)&wxT[nxt][col * 72 + 32 * rh + 4 * s] = wa;
      }
      __syncthreads();
    }
  }

  // epilogue: plain streaming stores to the private slot (no atomics)
  #pragma unroll
  for (int tm = 0; tm < 2; tm++)
    #pragma unroll
    for (int tn = 0; tn < 4; tn++)
      #pragma unroll
      for (int r = 0; r < 16; r++) {
        int row = mb + 32 * tm + (r & 3) + 8 * (r >> 2) + 4 * lh;
        int cg = nb + 32 * tn + l32;
        slot[row * 256 + cg] = acc[tm][tn][r];
      }
  atomicAdd(&wsf[OFF_COL + col], colAcc);
}

// ---------------- gfin: reduce 256 slots + bm regularizer ----------------
extern "C" __global__ __launch_bounds__(256) void gfin_k(float* __restrict__ wsf) {
  __shared__ float partial[4][256];
  const int tid = threadIdx.x;
  const int sg = tid >> 6, l = tid & 63;
  const int row = blockIdx.x;
  const float* slot0 = wsf + OFF_SLOT;
  f4v s = {0.f, 0.f, 0.f, 0.f};
  #pragma unroll 4
  for (int sl = sg; sl < 256; sl += 4)
    s += ((const f4v*)(slot0 + sl * 65536 + row * 256))[l];
  *(f4v*)&partial[sg][4 * l] = s;
  __syncthreads();
  float cr = wsf[OFF_COL + row];
  float ct = wsf[OFF_COL + tid];
  float gv = partial[0][tid] + partial[1][tid] + partial[2][tid] + partial[3][tid];
  float d = gv - cr * ct;
  float bm = (tid != row) ? d * d : 0.f;
  #pragma unroll
  for (int off = 32; off > 0; off >>= 1) bm += __shfl_down(bm, off);
  if (l == 0) atomicAdd(&wsf[5], bm);
}

// ---------------- mlp: hdn=relu(x@b1), dropout, logits, CE, argmax ----------------
// Round-1 geometry (4096 blocks x 64 rows, 256 thr, stride-40 staging,
// K-chunk 32) + register-prefetch pipeline ONLY (no du prefetch — that
// spilled in r3: WRITE_SIZE 86MB). Regs: 64 acc + 24 staging + ~15 addr
// ~= 103 < 128 cap of launch_bounds(256,4) -> no spill.
extern "C" __global__ __launch_bounds__(256, 4) void mlp_k(
    const float* __restrict__ x, const int* __restrict__ y,
    const float* __restrict__ du, float* __restrict__ wsf) {
  const __bf16* b1T = (const __bf16*)((const char*)wsf + B1T_BYTE);
  const __bf16* b2T = (const __bf16*)((const char*)wsf + B2T_BYTE);
  __shared__ union U {
    struct { __bf16 xs[64 * 40]; __bf16 b1s[256 * 40]; } m;   // 5120 + 20480 B
    struct { __bf16 hk[64 * 264]; float lg[64 * 17]; } l;     // 33792 + 4352 B
  } sm;
  const int tid = threadIdx.x;
  const int wv = tid >> 6, L = tid & 63;
  const int l32 = L & 31, lh = L >> 5;
  const int nb = 64 * wv;                    // wave owns 64 h-cols
  const int rowBase = blockIdx.x * 64;

  // staging index map (fixed per thread)
  const int xr = tid >> 3, xc = tid & 7;     // x: rows xr / xr+32, float4 group xc
  const int bnr = tid >> 2, bc = tid & 3;    // b1T: rows 64*i + bnr, v8bf group bc

  v16f acc[2][2] = {};
  f4v  xp0, xp1;
  v8bf bp0, bp1, bp2, bp3;

  // prologue: load chunk 0 into regs
  {
    const int kc = 0;
    xp0 = ((const f4v*)x)[(rowBase + xr) * 64 + (kc >> 2) + xc];
    xp1 = ((const f4v*)x)[(rowBase + 32 + xr) * 64 + (kc >> 2) + xc];
    bp0 = *(const v8bf*)&b1T[(bnr      ) * 256 + kc + 8 * bc];
    bp1 = *(const v8bf*)&b1T[(bnr +  64) * 256 + kc + 8 * bc];
    bp2 = *(const v8bf*)&b1T[(bnr + 128) * 256 + kc + 8 * bc];
    bp3 = *(const v8bf*)&b1T[(bnr + 192) * 256 + kc + 8 * bc];
  }

  #pragma unroll
  for (int ch = 0; ch < 8; ch++) {
    __syncthreads();                         // prev MFMA done reading LDS
    // write staged regs -> LDS
    {
      v4bf o;
      o[0] = (__bf16)xp0[0]; o[1] = (__bf16)xp0[1]; o[2] = (__bf16)xp0[2]; o[3] = (__bf16)xp0[3];
      *(v4bf*)&sm.m.xs[xr * 40 + 4 * xc] = o;
      o[0] = (__bf16)xp1[0]; o[1] = (__bf16)xp1[1]; o[2] = (__bf16)xp1[2]; o[3] = (__bf16)xp1[3];
      *(v4bf*)&sm.m.xs[(xr + 32) * 40 + 4 * xc] = o;
      *(v8bf*)&sm.m.b1s[(bnr      ) * 40 + 8 * bc] = bp0;
      *(v8bf*)&sm.m.b1s[(bnr +  64) * 40 + 8 * bc] = bp1;
      *(v8bf*)&sm.m.b1s[(bnr + 128) * 40 + 8 * bc] = bp2;
      *(v8bf*)&sm.m.b1s[(bnr + 192) * 40 + 8 * bc] = bp3;
    }
    __syncthreads();                         // LDS ready
    // issue next-chunk global loads (land during MFMA + next barrier)
    if (ch < 7) {
      const int kc = 32 * (ch + 1);
      xp0 = ((const f4v*)x)[(rowBase + xr) * 64 + (kc >> 2) + xc];
      xp1 = ((const f4v*)x)[(rowBase + 32 + xr) * 64 + (kc >> 2) + xc];
      bp0 = *(const v8bf*)&b1T[(bnr      ) * 256 + kc + 8 * bc];
      bp1 = *(const v8bf*)&b1T[(bnr +  64) * 256 + kc + 8 * bc];
      bp2 = *(const v8bf*)&b1T[(bnr + 128) * 256 + kc + 8 * bc];
      bp3 = *(const v8bf*)&b1T[(bnr + 192) * 256 + kc + 8 * bc];
    }
    // MFMA on staged chunk
    #pragma unroll
    for (int ks = 0; ks < 32; ks += 16) {
      v8bf a0  = *(const v8bf*)&sm.m.xs[(l32) * 40 + ks + 8 * lh];
      v8bf a1  = *(const v8bf*)&sm.m.xs[(32 + l32) * 40 + ks + 8 * lh];
      v8bf b0  = *(const v8bf*)&sm.m.b1s[(nb + l32) * 40 + ks + 8 * lh];
      v8bf b1f = *(const v8bf*)&sm.m.b1s[(nb + 32 + l32) * 40 + ks + 8 * lh];
      acc[0][0] = __builtin_amdgcn_mfma_f32_32x32x16_bf16(a0, b0,  acc[0][0], 0, 0, 0);
      acc[0][1] = __builtin_amdgcn_mfma_f32_32x32x16_bf16(a0, b1f, acc[0][1], 0, 0, 0);
      acc[1][0] = __builtin_amdgcn_mfma_f32_32x32x16_bf16(a1, b0,  acc[1][0], 0, 0, 0);
      acc[1][1] = __builtin_amdgcn_mfma_f32_32x32x16_bf16(a1, b1f, acc[1][1], 0, 0, 0);
    }
  }
  // relu + inverted dropout (C layout: col=lane&31, row=(r&3)+8*(r>>2)+4*lh)
  #pragma unroll
  for (int tm = 0; tm < 2; tm++)
    #pragma unroll
    for (int tn = 0; tn < 2; tn++)
      #pragma unroll
      for (int r = 0; r < 16; r++) {
        int row = 32 * tm + (r & 3) + 8 * (r >> 2) + 4 * lh;
        int cg = nb + 32 * tn + l32;
        float u = du[(rowBase + row) * 256 + cg];
        float v = acc[tm][tn][r];
        v = fmaxf(v, 0.f);
        acc[tm][tn][r] = (u > 0.3f) ? v * (1.0f / 0.7f) : 0.f;
      }

  // spill P to LDS full-width [64][264]
  __syncthreads();
  #pragma unroll
  for (int tm = 0; tm < 2; tm++)
    #pragma unroll
    for (int tn = 0; tn < 2; tn++)
      #pragma unroll
      for (int r = 0; r < 16; r++) {
        int row = 32 * tm + (r & 3) + 8 * (r >> 2) + 4 * lh;
        int cg = nb + 32 * tn + l32;
        sm.l.hk[row * 264 + cg] = (__bf16)acc[tm][tn][r];
      }
  __syncthreads();
  // logits: wave wv -> m-tile rows [16wv,16wv+16), K=256 via 8x 16x16x32
  v4f lacc = {};
  #pragma unroll
  for (int kk = 0; kk < 8; kk++) {
    v8bf a  = *(const v8bf*)&sm.l.hk[(16 * wv + (L & 15)) * 264 + 32 * kk + 8 * (L >> 4)];
    v8bf bb = *(const v8bf*)&b2T[(L & 15) * 256 + 32 * kk + 8 * (L >> 4)];
    lacc = __builtin_amdgcn_mfma_f32_16x16x32_bf16(a, bb, lacc, 0, 0, 0);
  }
  #pragma unroll
  for (int r = 0; r < 4; r++)
    sm.l.lg[(16 * wv + 4 * (L >> 4) + r) * 17 + (L & 15)] = lacc[r];
  __syncthreads();
  float ce = 0.f;
  int cor = 0;
  if (tid < 64) {
    const float* lr = &sm.l.lg[tid * 17];
    float mx = lr[0];
    int am = 0;
    #pragma unroll
    for (int c = 1; c < 10; c++)
      if (lr[c] > mx) { mx = lr[c]; am = c; }   // strict > = first-max (jnp semantics)
    float s = 0.f;
    #pragma unroll
    for (int c = 0; c < 10; c++) s += expf(lr[c] - mx);
    int yt = y[rowBase + tid];
    ce = logf(s) + mx - lr[yt];
    cor = (am == yt) ? 1 : 0;
  }
  if (wv == 0) {
    #pragma unroll
    for (int off = 32; off > 0; off >>= 1) ce += __shfl_down(ce, off);
    unsigned long long bal = __ballot(cor != 0);
    if (L == 0) {
      atomicAdd(&wsf[0], ce);
      atomicAdd((int*)&wsf[8], (int)__popcll(bal));
    }
  }
}

// ---------------- fin2: scalar combine ----------------
extern "C" __global__ void fin2_k(const float* __restrict__ wsf, float* __restrict__ out) {
  if (threadIdx.x == 0) {
    float ce = wsf[0], wsum = wsf[1], w4 = wsf[2], ab1 = wsf[3], ab2 = wsf[4], bm = wsf[5];
    int cor = ((const int*)wsf)[8];
    float loss = ce * wsum
               + 0.01f * (ab1 + ab2)
               + 0.001f * bm
               + 0.1f * w4
               + 100.f * (wsum - 1.f) * (wsum - 1.f);
    out[0] = loss;
    out[1] = (float)cor * (1.0f / 262144.0f);
  }
}

extern "C" void kernel_launch(void* const* d_in, const int* in_sizes, int n_in,
                              void* d_out, int out_size, void* d_ws, size_t ws_size,
                              hipStream_t stream) {
  const float* x  = (const float*)d_in[0];
  const int*   y  = (const int*)d_in[1];
  const float* du = (const float*)d_in[2];
  const float* b1 = (const float*)d_in[3];
  const float* b2 = (const float*)d_in[4];
  const float* w  = (const float*)d_in[5];
  float* wsf = (float*)d_ws;

  hipMemsetAsync(d_ws, 0, ZERO_BYTES, stream);   // scalars + col only
  prep_k<<<1024, 256, 0, stream>>>(w, b1, b2, wsf);
  gram_k<<<256, 512, 0, stream>>>(x, wsf);       // x stays warm in L3 for mlp
  gfin_k<<<256, 256, 0, stream>>>(wsf);          // slots are L3-hot right here
  mlp_k<<<4096, 256, 0, stream>>>(x, y, du, wsf);
  fin2_k<<<1, 64, 0, stream>>>(wsf, (float*)d_out);
}